// Round 15
// baseline (206.558 us; speedup 1.0000x reference)
//
#include <hip/hip_runtime.h>

#define H 512
#define W 512
#define TILE 64
#define NT 256
#define SW 104                // LDS row stride in halfs (52 dwords)
#define SROWS 90
#define TPD (W / TILE)        // 8 tiles per dim
#define NBANKS 16
#define BANK_STRIDE 16
// Tile px (y,x) at LDS (13+y, 16+x) fp16. Staging clamp-replicates borders.
//
// MEASURED HISTORY: R7 in-place 2-barrier/pass = 137us steady (VALUBusy
// 74.6, conflicts 2.05e7 hidden, occ 48, WRITE~0). R10 shuffle-edges 146us
// (issue-bound). R11 ping-pong 146us (occ 39.7). R14 diet+hoist 138-140us:
// hoisting ov0..ov3 across the R-loop spilled ONE float4/thread
// (WRITE_SIZE 256B->16.6MB, VALUBusy 74.6->67) and ate the diet's gain.
// THIS ROUND: same diet, hoist dropped -- other-image loads back in the
// epilogue (R7 placement, proven free): (1) sigmoid via v_rcp_f32
// (IEEE div ~9 ops -> 1; err 1e-7 << fp16 quantum), (2) min(b,c) CSE,
// (4) stage rows 1..89 (row 0 never read).
// ARBITRATION: WRITE_SIZE must return to ~256B; predicted 126-133us.
//
// In-place safety: pass R reads rows [12-R,78+R] == exactly the rows
// written by pass R+1; all reads (incl. t0) pre-barrier-A, writes between
// barriers A/B, dilate after B reads the new level only.
// COLUMN TRIM: pass R consumed on half-cols [16-R,79+R]; 12 groups R>=9,
// 10 groups (GLO=1) R<=8. V(11)=[1,94], V(10)=[2,93], V(9)=[3,92],
// V(R<=8)=[16-R,79+R] exact; stale cols advance 1/pass staying outside the
// consumed range; final dilate reads cols [15,80]=V(1), rows [12,77].
// items: min 330 (R=1) >= NT -> k=0 unconditional; >512 only at R=11 -> K2.

typedef _Float16 h8 __attribute__((ext_vector_type(8)));
typedef _Float16 h4 __attribute__((ext_vector_type(4)));

__device__ __forceinline__ float sigmf(float x) {
  // 1/(1+e^-x) with hw rcp: full IEEE divide is ~9 VALU ops, rcp is 1.
  return __builtin_amdgcn_rcpf(1.0f + __expf(-x));
}
__device__ __forceinline__ float4 ld4(const float* p) { return *(const float4*)p; }

__device__ __forceinline__ h8 min3v(h8 a, h8 b, h8 c) {
  return __builtin_elementwise_min(__builtin_elementwise_min(a, b), c);
}
__device__ __forceinline__ h8 max3v(h8 a, h8 b, h8 c) {
  return __builtin_elementwise_max(__builtin_elementwise_max(a, b), c);
}
__device__ __forceinline__ h8 shl1(h8 v, _Float16 e) {
  h8 r = __builtin_shufflevector(v, v, 7, 0, 1, 2, 3, 4, 5, 6);
  r[0] = e;
  return r;
}
__device__ __forceinline__ h8 shr1(h8 v, _Float16 e) {
  h8 r = __builtin_shufflevector(v, v, 1, 2, 3, 4, 5, 6, 7, 0);
  r[7] = e;
  return r;
}
// b32 loads of half pairs (keeps ds_read2 mergeability), extract one half.
__device__ __forceinline__ _Float16 hi_half(const _Float16* p) {
  unsigned v = *(const unsigned*)p;
  return __builtin_bit_cast(_Float16, (unsigned short)(v >> 16));
}
__device__ __forceinline__ _Float16 lo_half(const _Float16* p) {
  unsigned v = *(const unsigned*)p;
  return __builtin_bit_cast(_Float16, (unsigned short)v);
}
__device__ __forceinline__ _Float16 hmax3(_Float16 a, _Float16 b, _Float16 c) {
  _Float16 m = a > b ? a : b;
  return m > c ? m : c;
}

// Erode 3x1/1x3-min stencil for a row pair at (r0, group gg): outputs oA
// (row r0) and oB (row r0+1). Reads rows r0-1..r0+2. m=min(b,c) shared.
#define ERODE_AT(r0, gg, oA, oB)                                          \
  {                                                                       \
    const _Float16* s0 = buf + ((r0)-1) * SW + 8 * (GLO + (gg));          \
    h8 a = *(const h8*)(s0);                                              \
    h8 b = *(const h8*)(s0 + SW);                                         \
    h8 c = *(const h8*)(s0 + 2 * SW);                                     \
    h8 d = *(const h8*)(s0 + 3 * SW);                                     \
    _Float16 le0 = hi_half(s0 + SW - 2);                                  \
    _Float16 le1 = hi_half(s0 + 2 * SW - 2);                              \
    _Float16 re0 = lo_half(s0 + SW + 8);                                  \
    _Float16 re1 = lo_half(s0 + 2 * SW + 8);                              \
    h8 m = __builtin_elementwise_min(b, c);                               \
    oA = __builtin_elementwise_min(                                       \
        __builtin_elementwise_min(__builtin_elementwise_min(a, m),        \
                                  shl1(b, le0)),                          \
        shr1(b, re0));                                                    \
    oB = __builtin_elementwise_min(                                       \
        __builtin_elementwise_min(__builtin_elementwise_min(m, d),        \
                                  shl1(c, le1)),                          \
        shr1(c, re1));                                                    \
  }

#define WRITE_AT(r0, gg, oA, oB)                             \
  {                                                          \
    _Float16* d0 = buf + (r0)*SW + 8 * (GLO + (gg));         \
    *(h8*)(d0) = oA;                                         \
    *(h8*)(d0 + SW) = oB;                                    \
  }

// One full in-place erode pass (compute -> barrier -> write -> barrier).
// All state in named registers spanning the barriers (R2 scratch lesson).
template <int G, int GLO, bool K2>
__device__ __forceinline__ void erode_pass(_Float16* buf, int tid, int rb,
                                           int items) {
  const int rp0 = tid / G;  // G compile-time: magic-multiply
  const int g0 = tid - rp0 * G;
  const int r00 = rb + 2 * rp0;

  const int it1 = tid + NT;
  const bool a1 = it1 < items;
  const int rp1 = it1 / G;
  const int g1 = it1 - rp1 * G;
  const int r01 = rb + 2 * rp1;

  const int it2 = tid + 2 * NT;
  const bool a2 = K2 && (it2 < items);
  const int rp2 = it2 / G;
  const int g2 = it2 - rp2 * G;
  const int r02 = rb + 2 * rp2;

  h8 o00, o01, o10, o11, o20, o21;
  ERODE_AT(r00, g0, o00, o01);            // k=0 always active (items>=330)
  if (a1) ERODE_AT(r01, g1, o10, o11);
  if (K2) {
    if (a2) ERODE_AT(r02, g2, o20, o21);
  }

  __syncthreads();  // A: all reads of the old level complete

  WRITE_AT(r00, g0, o00, o01);
  if (a1) WRITE_AT(r01, g1, o10, o11);
  if (K2) {
    if (a2) WRITE_AT(r02, g2, o20, o21);
  }

  __syncthreads();  // B: new level fully in buf
}

__global__ __launch_bounds__(NT, 5) void cl_skel_kernel(
    const float* __restrict__ pred, const float* __restrict__ target,
    double* __restrict__ sums) {
  __shared__ _Float16 buf[SROWS * SW];
  __shared__ float rbuf[2][NT / 64];

  const int tid = threadIdx.x;
  const int tileIdx = blockIdx.x;
  const int batch = blockIdx.y;
  const bool isPred = (blockIdx.z == 0);
  const int tr = (tileIdx / TPD) * TILE;
  const int tc = (tileIdx % TPD) * TILE;
  const float* __restrict__ img = isPred ? pred : target;
  const float* __restrict__ other = isPred ? target : pred;
  const size_t base = (size_t)batch * (H * W);

  const bool border = (tr == 0) | (tc == 0) | (tr == H - TILE) | (tc == W - TILE);

  // ---- Stage x0 (fp16): LDS rows 1..89 (row 0 never read), cols 0..95 ----
  if (!border) {
    for (int it = tid; it < 89 * 24; it += NT) {
      int row = 1 + it / 24, g = it - (row - 1) * 24;
      int gr = tr - 13 + row;
      int gc = tc - 16 + 4 * g;
      float4 v = ld4(&img[base + (size_t)gr * W + gc]);
      if (isPred) {
        v.x = sigmf(v.x); v.y = sigmf(v.y); v.z = sigmf(v.z); v.w = sigmf(v.w);
      }
      h4 hv;
      hv[0] = (_Float16)v.x; hv[1] = (_Float16)v.y;
      hv[2] = (_Float16)v.z; hv[3] = (_Float16)v.w;
      *(h4*)(buf + row * SW + 4 * g) = hv;
    }
  } else {
    for (int it = tid; it < 89 * 24; it += NT) {
      int row = 1 + it / 24, g = it - (row - 1) * 24;
      int gr = min(max(tr - 13 + row, 0), H - 1);
      int gc = tc - 16 + 4 * g;
      float4 v;
      v.x = img[base + (size_t)gr * W + min(max(gc + 0, 0), W - 1)];
      v.y = img[base + (size_t)gr * W + min(max(gc + 1, 0), W - 1)];
      v.z = img[base + (size_t)gr * W + min(max(gc + 2, 0), W - 1)];
      v.w = img[base + (size_t)gr * W + min(max(gc + 3, 0), W - 1)];
      if (isPred) {
        v.x = sigmf(v.x); v.y = sigmf(v.y); v.z = sigmf(v.z); v.w = sigmf(v.w);
      }
      h4 hv;
      hv[0] = (_Float16)v.x; hv[1] = (_Float16)v.y;
      hv[2] = (_Float16)v.z; hv[3] = (_Float16)v.w;
      *(h4*)(buf + row * SW + 4 * g) = hv;
    }
  }
  __syncthreads();

  const int ty = tid >> 2;  // 0..63: own tile row
  const int tg = tid & 3;   // 0..3 : own 16-col group
  const int rr = 13 + ty;
  const int c0 = 16 + 16 * tg;

  h8 skelE = (h8)(_Float16)0.0f;
  h8 skelF = (h8)(_Float16)0.0f;

#pragma unroll 1
  for (int R = 11; R >= 1; --R) {
    const int rb = 13 - R;

    // t0 = x_{k-1} at own 16 px — read before any in-place write (pre-barrier A)
    const _Float16* ps = buf + rr * SW + c0;
    h8 t0E = *(const h8*)ps;
    h8 t0F = *(const h8*)(ps + 8);

    if (R == 11) {
      erode_pass<12, 0, true>(buf, tid, rb, 43 * 12);
    } else if (R >= 9) {
      erode_pass<12, 0, false>(buf, tid, rb, (32 + R) * 12);
    } else {
      erode_pass<10, 1, false>(buf, tid, rb, (32 + R) * 10);
    }

    // ---- dilate(buf) at own 16 px; skel update ----
    {
      const _Float16* pm = buf + (rr - 1) * SW + c0;
      h8 aE = *(const h8*)(pm),          aF = *(const h8*)(pm + 8);
      h8 bE = *(const h8*)(pm + SW),     bF = *(const h8*)(pm + SW + 8);
      h8 cE = *(const h8*)(pm + 2 * SW), cF = *(const h8*)(pm + 2 * SW + 8);
      _Float16 vl = hmax3(hi_half(pm - 2), hi_half(pm + SW - 2),
                          hi_half(pm + 2 * SW - 2));
      _Float16 vr = hmax3(lo_half(pm + 16), lo_half(pm + SW + 16),
                          lo_half(pm + 2 * SW + 16));
      h8 vmE = max3v(aE, bE, cE);
      h8 vmF = max3v(aF, bF, cF);
      h8 hE = max3v(shl1(vmE, vl), vmE, shr1(vmE, vmF[0]));
      h8 hF = max3v(shl1(vmF, vmE[7]), vmF, shr1(vmF, vr));
      h8 z = (h8)(_Float16)0.0f;
      h8 dE = __builtin_elementwise_max(t0E - hE, z);
      h8 dF = __builtin_elementwise_max(t0F - hF, z);
      skelE += __builtin_elementwise_max(dE - skelE * dE, z);
      skelF += __builtin_elementwise_max(dF - skelF * dF, z);
    }
    // next pass reads buf (level R) pre-its-barrier-A: reads only, safe.
  }

  // ---- Products with the other image over own 16 px (loads in epilogue,
  // R7 placement: no cross-loop register pressure) ----
  const float* orow = other + base + (size_t)(tr + ty) * W + tc + 16 * tg;
  float s0 = 0.0f, s1 = 0.0f;
#pragma unroll
  for (int q = 0; q < 4; ++q) {
    float4 o = ld4(orow + 4 * q);
    if (!isPred) {
      o.x = sigmf(o.x); o.y = sigmf(o.y); o.z = sigmf(o.z); o.w = sigmf(o.w);
    }
    float sk0, sk1, sk2, sk3;
    if (q < 2) {
      sk0 = (float)skelE[4 * q + 0]; sk1 = (float)skelE[4 * q + 1];
      sk2 = (float)skelE[4 * q + 2]; sk3 = (float)skelE[4 * q + 3];
    } else {
      sk0 = (float)skelF[4 * q - 8]; sk1 = (float)skelF[4 * q - 7];
      sk2 = (float)skelF[4 * q - 6]; sk3 = (float)skelF[4 * q - 5];
    }
    s0 += (sk0 + sk1) + (sk2 + sk3);
    s1 += (sk0 * o.x + sk1 * o.y) + (sk2 * o.z + sk3 * o.w);
  }

#pragma unroll
  for (int off = 32; off > 0; off >>= 1) {
    s0 += __shfl_down(s0, off, 64);
    s1 += __shfl_down(s1, off, 64);
  }
  const int wave = tid >> 6;
  const int lane = tid & 63;
  if (lane == 0) {
    rbuf[0][wave] = s0;
    rbuf[1][wave] = s1;
  }
  __syncthreads();
  if (tid == 0) {
    float t0 = 0.0f, t1 = 0.0f;
#pragma unroll
    for (int w = 0; w < NT / 64; ++w) {
      t0 += rbuf[0][w];
      t1 += rbuf[1][w];
    }
    const int bank = (int)(blockIdx.x & (NBANKS - 1));
    const int o2 = (isPred ? 0 : 2);
    atomicAdd(&sums[bank * BANK_STRIDE + o2], (double)t0);
    atomicAdd(&sums[bank * BANK_STRIDE + o2 + 1], (double)t1);
  }
}

__global__ void cl_finalize_kernel(const double* __restrict__ sums,
                                   float* __restrict__ out) {
  double s[4] = {0.0, 0.0, 0.0, 0.0};
  for (int b = 0; b < NBANKS; ++b)
    for (int j = 0; j < 4; ++j) s[j] += sums[b * BANK_STRIDE + j];
  double tprec = (s[1] + 1.0) / (s[0] + 1.0);
  double tsens = (s[3] + 1.0) / (s[2] + 1.0);
  double cl = 2.0 * tprec * tsens / (tprec + tsens + 1e-7);
  out[0] = (float)(1.0 - cl);
}

extern "C" void kernel_launch(void* const* d_in, const int* in_sizes, int n_in,
                              void* d_out, int out_size, void* d_ws,
                              size_t ws_size, hipStream_t stream) {
  const float* pred = (const float*)d_in[0];
  const float* target = (const float*)d_in[1];
  double* sums = (double*)d_ws;
  const int batch = in_sizes[0] / (H * W);  // 32

  hipMemsetAsync(d_ws, 0, NBANKS * BANK_STRIDE * sizeof(double), stream);
  dim3 grid(TPD * TPD, batch, 2);
  cl_skel_kernel<<<grid, NT, 0, stream>>>(pred, target, sums);
  cl_finalize_kernel<<<1, 1, 0, stream>>>(sums, (float*)d_out);
}

// Round 16
// 198.070 us; speedup vs baseline: 1.0429x; 1.0429x over previous
//
#include <hip/hip_runtime.h>

#define H 512
#define W 512
#define TH 64                 // tile rows
#define TW 128                // tile cols
#define NT 512
#define SW 168                // LDS row stride in halfs (84 dwords; 8 staged-pad)
#define SROWS 90
#define NBANKS 16
#define BANK_STRIDE 16
// 64x128 tile, px (y,x) at LDS (13+y, 16+x) fp16, staged cols 0..159
// (pad 160..167 uninit -- feeds only never-consumed edge cols, see proof).
//
// MEASURED HISTORY: R7 in-place 64x64 = 137us; R15 +diet (rcp-sigmoid,
// min-CSE, row-trim) = 135us champion, WRITE_SIZE 256B, VGPR 44, VALUBusy
// 69, conflicts 2.05e7 (hidden). Fine-grain diet exhausted. THIS ROUND:
// 64x128 tile, NT=512. Per output px: erode items 1.082->0.949 (-12%),
// staging 2.09->1.74 (-17%), barriers halved. LDS 30.2KB (R7 18.9->R11
// 37.9KB only cost 8 occ points, so 30KB ~free). k<=2 erode items/thread.
//
// In-place safety (rows identical to 64x64): pass R writes rows
// [13-R,76+R], reads [12-R,77+R] == prev pass's written rows; all reads
// pre-barrier-A, writes A->B, dilate after B. Stage rows 1..89 (R=11
// reads rows [1,88]).
// COLUMN TRIM/validity: pass R consumed cols [16-R,143+R]. G=20/GLO=0
// (R>=9, writes cols [0,159]), G=18/GLO=1 (R<=8, writes [8,151]).
// V(11)=[1,158], V(10)=[2,157], V(9)=[3,156], V(8)=[8,151], V(7)=[9,150],
// ..., V(1)=[15,144] exact = final dilate cols; margin >=0 at every pass
// (stale/garbage cols advance 1/pass, always outside consumed range).
// items: min 594 (R=1) >= NT -> k=0 unconditional; max 860 < 2*NT -> k=1
// guarded only.

typedef _Float16 h8 __attribute__((ext_vector_type(8)));
typedef _Float16 h4 __attribute__((ext_vector_type(4)));

__device__ __forceinline__ float sigmf(float x) {
  // 1/(1+e^-x) with hw rcp: full IEEE divide is ~9 VALU ops, rcp is 1.
  return __builtin_amdgcn_rcpf(1.0f + __expf(-x));
}
__device__ __forceinline__ float4 ld4(const float* p) { return *(const float4*)p; }

__device__ __forceinline__ h8 max3v(h8 a, h8 b, h8 c) {
  return __builtin_elementwise_max(__builtin_elementwise_max(a, b), c);
}
__device__ __forceinline__ h8 shl1(h8 v, _Float16 e) {
  h8 r = __builtin_shufflevector(v, v, 7, 0, 1, 2, 3, 4, 5, 6);
  r[0] = e;
  return r;
}
__device__ __forceinline__ h8 shr1(h8 v, _Float16 e) {
  h8 r = __builtin_shufflevector(v, v, 1, 2, 3, 4, 5, 6, 7, 0);
  r[7] = e;
  return r;
}
// b32 loads of half pairs (keeps ds_read2 mergeability), extract one half.
__device__ __forceinline__ _Float16 hi_half(const _Float16* p) {
  unsigned v = *(const unsigned*)p;
  return __builtin_bit_cast(_Float16, (unsigned short)(v >> 16));
}
__device__ __forceinline__ _Float16 lo_half(const _Float16* p) {
  unsigned v = *(const unsigned*)p;
  return __builtin_bit_cast(_Float16, (unsigned short)v);
}
__device__ __forceinline__ _Float16 hmax3(_Float16 a, _Float16 b, _Float16 c) {
  _Float16 m = a > b ? a : b;
  return m > c ? m : c;
}

// Erode 3x1/1x3-min stencil for a row pair at (r0, group gg): outputs oA
// (row r0) and oB (row r0+1). Reads rows r0-1..r0+2. m=min(b,c) shared.
#define ERODE_AT(r0, gg, oA, oB)                                          \
  {                                                                       \
    const _Float16* s0 = buf + ((r0)-1) * SW + 8 * (GLO + (gg));          \
    h8 a = *(const h8*)(s0);                                              \
    h8 b = *(const h8*)(s0 + SW);                                         \
    h8 c = *(const h8*)(s0 + 2 * SW);                                     \
    h8 d = *(const h8*)(s0 + 3 * SW);                                     \
    _Float16 le0 = hi_half(s0 + SW - 2);                                  \
    _Float16 le1 = hi_half(s0 + 2 * SW - 2);                              \
    _Float16 re0 = lo_half(s0 + SW + 8);                                  \
    _Float16 re1 = lo_half(s0 + 2 * SW + 8);                              \
    h8 m = __builtin_elementwise_min(b, c);                               \
    oA = __builtin_elementwise_min(                                       \
        __builtin_elementwise_min(__builtin_elementwise_min(a, m),        \
                                  shl1(b, le0)),                          \
        shr1(b, re0));                                                    \
    oB = __builtin_elementwise_min(                                       \
        __builtin_elementwise_min(__builtin_elementwise_min(m, d),        \
                                  shl1(c, le1)),                          \
        shr1(c, re1));                                                    \
  }

#define WRITE_AT(r0, gg, oA, oB)                             \
  {                                                          \
    _Float16* d0 = buf + (r0)*SW + 8 * (GLO + (gg));         \
    *(h8*)(d0) = oA;                                         \
    *(h8*)(d0 + SW) = oB;                                    \
  }

// One full in-place erode pass (compute -> barrier -> write -> barrier).
// All state in named registers spanning the barriers (R2 scratch lesson).
template <int G, int GLO>
__device__ __forceinline__ void erode_pass(_Float16* buf, int tid, int rb,
                                           int items) {
  const int rp0 = tid / G;  // G compile-time: magic-multiply
  const int g0 = tid - rp0 * G;
  const int r00 = rb + 2 * rp0;

  const int it1 = tid + NT;
  const bool a1 = it1 < items;
  const int rp1 = it1 / G;
  const int g1 = it1 - rp1 * G;
  const int r01 = rb + 2 * rp1;

  h8 o00, o01, o10, o11;
  ERODE_AT(r00, g0, o00, o01);            // k=0 always active (items>=594)
  if (a1) ERODE_AT(r01, g1, o10, o11);

  __syncthreads();  // A: all reads of the old level complete

  WRITE_AT(r00, g0, o00, o01);
  if (a1) WRITE_AT(r01, g1, o10, o11);

  __syncthreads();  // B: new level fully in buf
}

__global__ __launch_bounds__(NT, 4) void cl_skel_kernel(
    const float* __restrict__ pred, const float* __restrict__ target,
    double* __restrict__ sums) {
  __shared__ _Float16 buf[SROWS * SW];
  __shared__ float rbuf[2][NT / 64];

  const int tid = threadIdx.x;
  const int tileIdx = blockIdx.x;        // 0..31: 8 row-tiles x 4 col-tiles
  const int batch = blockIdx.y;
  const bool isPred = (blockIdx.z == 0);
  const int tr = (tileIdx >> 2) * TH;
  const int tc = (tileIdx & 3) * TW;
  const float* __restrict__ img = isPred ? pred : target;
  const float* __restrict__ other = isPred ? target : pred;
  const size_t base = (size_t)batch * (H * W);

  const bool border = (tr == 0) | (tc == 0) | (tr == H - TH) | (tc == W - TW);

  // ---- Stage x0 (fp16): LDS rows 1..89, half cols 0..159 (40 f4 groups) ----
  if (!border) {
    for (int it = tid; it < 89 * 40; it += NT) {
      int row = 1 + it / 40, g = it - (row - 1) * 40;
      int gr = tr - 13 + row;
      int gc = tc - 16 + 4 * g;
      float4 v = ld4(&img[base + (size_t)gr * W + gc]);
      if (isPred) {
        v.x = sigmf(v.x); v.y = sigmf(v.y); v.z = sigmf(v.z); v.w = sigmf(v.w);
      }
      h4 hv;
      hv[0] = (_Float16)v.x; hv[1] = (_Float16)v.y;
      hv[2] = (_Float16)v.z; hv[3] = (_Float16)v.w;
      *(h4*)(buf + row * SW + 4 * g) = hv;
    }
  } else {
    for (int it = tid; it < 89 * 40; it += NT) {
      int row = 1 + it / 40, g = it - (row - 1) * 40;
      int gr = min(max(tr - 13 + row, 0), H - 1);
      int gc = tc - 16 + 4 * g;
      float4 v;
      v.x = img[base + (size_t)gr * W + min(max(gc + 0, 0), W - 1)];
      v.y = img[base + (size_t)gr * W + min(max(gc + 1, 0), W - 1)];
      v.z = img[base + (size_t)gr * W + min(max(gc + 2, 0), W - 1)];
      v.w = img[base + (size_t)gr * W + min(max(gc + 3, 0), W - 1)];
      if (isPred) {
        v.x = sigmf(v.x); v.y = sigmf(v.y); v.z = sigmf(v.z); v.w = sigmf(v.w);
      }
      h4 hv;
      hv[0] = (_Float16)v.x; hv[1] = (_Float16)v.y;
      hv[2] = (_Float16)v.z; hv[3] = (_Float16)v.w;
      *(h4*)(buf + row * SW + 4 * g) = hv;
    }
  }
  __syncthreads();

  const int ty = tid >> 3;  // 0..63: own tile row
  const int tg = tid & 7;   // 0..7 : own 16-col group
  const int rr = 13 + ty;
  const int c0 = 16 + 16 * tg;

  h8 skelE = (h8)(_Float16)0.0f;
  h8 skelF = (h8)(_Float16)0.0f;

#pragma unroll 1
  for (int R = 11; R >= 1; --R) {
    const int rb = 13 - R;

    // t0 = x_{k-1} at own 16 px — read before any in-place write (pre-barrier A)
    const _Float16* ps = buf + rr * SW + c0;
    h8 t0E = *(const h8*)ps;
    h8 t0F = *(const h8*)(ps + 8);

    if (R >= 9) {
      erode_pass<20, 0>(buf, tid, rb, (32 + R) * 20);
    } else {
      erode_pass<18, 1>(buf, tid, rb, (32 + R) * 18);
    }

    // ---- dilate(buf) at own 16 px; skel update ----
    {
      const _Float16* pm = buf + (rr - 1) * SW + c0;
      h8 aE = *(const h8*)(pm),          aF = *(const h8*)(pm + 8);
      h8 bE = *(const h8*)(pm + SW),     bF = *(const h8*)(pm + SW + 8);
      h8 cE = *(const h8*)(pm + 2 * SW), cF = *(const h8*)(pm + 2 * SW + 8);
      _Float16 vl = hmax3(hi_half(pm - 2), hi_half(pm + SW - 2),
                          hi_half(pm + 2 * SW - 2));
      _Float16 vr = hmax3(lo_half(pm + 16), lo_half(pm + SW + 16),
                          lo_half(pm + 2 * SW + 16));
      h8 vmE = max3v(aE, bE, cE);
      h8 vmF = max3v(aF, bF, cF);
      h8 hE = max3v(shl1(vmE, vl), vmE, shr1(vmE, vmF[0]));
      h8 hF = max3v(shl1(vmF, vmE[7]), vmF, shr1(vmF, vr));
      h8 z = (h8)(_Float16)0.0f;
      h8 dE = __builtin_elementwise_max(t0E - hE, z);
      h8 dF = __builtin_elementwise_max(t0F - hF, z);
      skelE += __builtin_elementwise_max(dE - skelE * dE, z);
      skelF += __builtin_elementwise_max(dF - skelF * dF, z);
    }
    // next pass reads buf (level R) pre-its-barrier-A: reads only, safe.
  }

  // ---- Products with the other image over own 16 px (epilogue loads) ----
  const float* orow = other + base + (size_t)(tr + ty) * W + tc + 16 * tg;
  float s0 = 0.0f, s1 = 0.0f;
#pragma unroll
  for (int q = 0; q < 4; ++q) {
    float4 o = ld4(orow + 4 * q);
    if (!isPred) {
      o.x = sigmf(o.x); o.y = sigmf(o.y); o.z = sigmf(o.z); o.w = sigmf(o.w);
    }
    float sk0, sk1, sk2, sk3;
    if (q < 2) {
      sk0 = (float)skelE[4 * q + 0]; sk1 = (float)skelE[4 * q + 1];
      sk2 = (float)skelE[4 * q + 2]; sk3 = (float)skelE[4 * q + 3];
    } else {
      sk0 = (float)skelF[4 * q - 8]; sk1 = (float)skelF[4 * q - 7];
      sk2 = (float)skelF[4 * q - 6]; sk3 = (float)skelF[4 * q - 5];
    }
    s0 += (sk0 + sk1) + (sk2 + sk3);
    s1 += (sk0 * o.x + sk1 * o.y) + (sk2 * o.z + sk3 * o.w);
  }

#pragma unroll
  for (int off = 32; off > 0; off >>= 1) {
    s0 += __shfl_down(s0, off, 64);
    s1 += __shfl_down(s1, off, 64);
  }
  const int wave = tid >> 6;
  const int lane = tid & 63;
  if (lane == 0) {
    rbuf[0][wave] = s0;
    rbuf[1][wave] = s1;
  }
  __syncthreads();
  if (tid == 0) {
    float t0 = 0.0f, t1 = 0.0f;
#pragma unroll
    for (int w = 0; w < NT / 64; ++w) {
      t0 += rbuf[0][w];
      t1 += rbuf[1][w];
    }
    const int bank = (int)(blockIdx.x & (NBANKS - 1));
    const int o2 = (isPred ? 0 : 2);
    atomicAdd(&sums[bank * BANK_STRIDE + o2], (double)t0);
    atomicAdd(&sums[bank * BANK_STRIDE + o2 + 1], (double)t1);
  }
}

__global__ void cl_finalize_kernel(const double* __restrict__ sums,
                                   float* __restrict__ out) {
  double s[4] = {0.0, 0.0, 0.0, 0.0};
  for (int b = 0; b < NBANKS; ++b)
    for (int j = 0; j < 4; ++j) s[j] += sums[b * BANK_STRIDE + j];
  double tprec = (s[1] + 1.0) / (s[0] + 1.0);
  double tsens = (s[3] + 1.0) / (s[2] + 1.0);
  double cl = 2.0 * tprec * tsens / (tprec + tsens + 1e-7);
  out[0] = (float)(1.0 - cl);
}

extern "C" void kernel_launch(void* const* d_in, const int* in_sizes, int n_in,
                              void* d_out, int out_size, void* d_ws,
                              size_t ws_size, hipStream_t stream) {
  const float* pred = (const float*)d_in[0];
  const float* target = (const float*)d_in[1];
  double* sums = (double*)d_ws;
  const int batch = in_sizes[0] / (H * W);  // 32

  hipMemsetAsync(d_ws, 0, NBANKS * BANK_STRIDE * sizeof(double), stream);
  dim3 grid((H / TH) * (W / TW), batch, 2);
  cl_skel_kernel<<<grid, NT, 0, stream>>>(pred, target, sums);
  cl_finalize_kernel<<<1, 1, 0, stream>>>(sums, (float*)d_out);
}